// Round 1
// 670.796 us; speedup vs baseline: 1.0380x; 1.0380x over previous
//
#include <hip/hip_runtime.h>

// ===========================================================================
// CrossAttention (B=32, TF=2048, TP=256, F=768, P=512, A=512).
// Round 1: async staging (global_load_lds + XOR swizzle), double-buffered
// LDS with 1 barrier/step, reg-prefetched A with packed bf16 cvt, Q-in-reg
// attn phase1, T14 early-issue phase3, T5 setprio, XCD block swizzle.
// ===========================================================================

typedef __bf16 bf16x8 __attribute__((ext_vector_type(8)));
typedef __bf16 bf16x4 __attribute__((ext_vector_type(4)));
typedef float  f32x4  __attribute__((ext_vector_type(4)));
typedef int    i32x4  __attribute__((ext_vector_type(4)));
typedef int    i32x2  __attribute__((ext_vector_type(2)));
typedef unsigned short u16;

__device__ __forceinline__ u16 f2b(float f) {   // round-to-nearest-even
  union { float f; unsigned int i; } v; v.f = f;
  unsigned int u = v.i;
  return (u16)((u + 0x7FFFu + ((u >> 16) & 1u)) >> 16);
}
__device__ __forceinline__ bf16x8 ldfrag(const u16* p) {
  return __builtin_bit_cast(bf16x8, *(const i32x4*)p);
}
__device__ __forceinline__ f32x4 mfma16(bf16x8 a, bf16x8 b, f32x4 c) {
  return __builtin_amdgcn_mfma_f32_16x16x32_bf16(a, b, c, 0, 0, 0);
}
// async global->LDS, 16B per lane; LDS dest is wave-uniform base + lane*16
__device__ __forceinline__ void gl_lds16(const void* g, void* l) {
  __builtin_amdgcn_global_load_lds(
      (const __attribute__((address_space(1))) void*)g,
      (__attribute__((address_space(3))) void*)l, 16, 0, 0);
}

// --------------------------------------------------------------------------
// out[C][R] (bf16) = in[R][C]^T (fp32). For weights.
// --------------------------------------------------------------------------
__global__ void transpose_f32_bf16(const float* __restrict__ in, u16* __restrict__ out,
                                   int R, int C) {
  __shared__ u16 tile[32][33];
  int c0 = blockIdx.x * 32, r0 = blockIdx.y * 32;
  int x = threadIdx.x, y = threadIdx.y;  // x:0..31, y:0..7
#pragma unroll
  for (int i = 0; i < 32; i += 8) tile[y + i][x] = f2b(in[(size_t)(r0 + y + i) * C + c0 + x]);
  __syncthreads();
#pragma unroll
  for (int i = 0; i < 32; i += 8) out[(size_t)(c0 + y + i) * R + r0 + x] = tile[x][y + i];
}

// --------------------------------------------------------------------------
// bf16 2D transpose, batched via blockIdx.z (for Kp -> KpT).
// --------------------------------------------------------------------------
__global__ void transpose_bf16(const u16* __restrict__ in, u16* __restrict__ out,
                               int R, int C, long inStride, long outStride) {
  __shared__ u16 tile[32][33];
  long bb = blockIdx.z;
  in  += bb * inStride;
  out += bb * outStride;
  int c0 = blockIdx.x * 32, r0 = blockIdx.y * 32;
  int x = threadIdx.x, y = threadIdx.y;
#pragma unroll
  for (int i = 0; i < 32; i += 8) tile[y + i][x] = in[(size_t)(r0 + y + i) * C + c0 + x];
  __syncthreads();
#pragma unroll
  for (int i = 0; i < 32; i += 8) out[(size_t)(c0 + y + i) * R + r0 + x] = tile[x][y + i];
}

// --------------------------------------------------------------------------
// C[M][N] (bf16) = A[M][K] (fp32, converted during staging) @ Bt[N][K]^T (bf16)
// + bias[N].  128x128 tile, BK=64, double-buffered LDS, 1 barrier/K-step.
// B staged via global_load_lds into linear [128][64] with XOR-swizzled source;
// A reg-prefetched and packed-converted.  N==512 assumed (nbx=4), grid 1D.
// --------------------------------------------------------------------------
__global__ __launch_bounds__(256, 2) void gemm_bias_bt(
    const float* __restrict__ A, const u16* __restrict__ Bt,
    const float* __restrict__ bias, u16* __restrict__ C, int M, int N, int K) {
  __shared__ __align__(16) u16 As[2][128][72];   // padded: 144B rows, 2-way free
  __shared__ __align__(16) u16 Bs[2][128][64];   // linear: 128B rows, XOR-swizzled
  int tid = threadIdx.x, wave = tid >> 6, lane = tid & 63;
  int l = lane & 15, q = lane >> 4;
  int wr = wave >> 1, wc = wave & 1;

  // XCD-chunked swizzle: XCD k gets a contiguous range of original ids.
  int chunk = gridDim.x >> 3;
  int swz = (blockIdx.x & 7) * chunk + (blockIdx.x >> 3);
  int n0 = (swz & 3) * 128, m0 = (swz >> 2) * 128;

  int aRow = tid >> 4, aCol = (tid & 15) * 4;   // A: fp32 x4 per thread
  int NT = K >> 6;
  int sw = ((lane & 7) ^ (lane >> 3)) << 4;     // source-address XOR (bytes)

  f32x4 acc[4][4];
#pragma unroll
  for (int mt = 0; mt < 4; mt++)
#pragma unroll
    for (int nt = 0; nt < 4; nt++) acc[mt][nt] = (f32x4)0.0f;
  f32x4 pf[8];

  auto stageB = [&](int buf, int kc) {
#pragma unroll
    for (int i = 0; i < 4; i++) {
      int rb = wave * 4 + i;                 // 1KB chunk (8 rows) id 0..15
      int r  = rb * 8 + (lane >> 3);
      const char* src = (const char*)Bt + ((size_t)(n0 + r) * K + kc) * 2 + sw;
      gl_lds16(src, (char*)&Bs[buf][0][0] + rb * 1024);
    }
  };
  auto loadA = [&](int kc) {
#pragma unroll
    for (int i = 0; i < 8; i++)
      pf[i] = *(const f32x4*)&A[(size_t)(m0 + aRow + i * 16) * K + kc + aCol];
  };
  auto writeA = [&](int buf) {
#pragma unroll
    for (int i = 0; i < 8; i++) {
      bf16x4 h;
#pragma unroll
      for (int j = 0; j < 4; j++) h[j] = (__bf16)pf[i][j];
      *(i32x2*)&As[buf][aRow + i * 16][aCol] = __builtin_bit_cast(i32x2, h);
    }
  };

  stageB(0, 0);
  loadA(0);
  writeA(0);
  __syncthreads();

  for (int t = 0; t < NT; t++) {
    int cur = t & 1, nxt = cur ^ 1;
    bool more = (t + 1 < NT);
    if (more) { stageB(nxt, (t + 1) << 6); loadA((t + 1) << 6); }
#pragma unroll
    for (int ks = 0; ks < 64; ks += 32) {
      bf16x8 af[4], bv[4];
#pragma unroll
      for (int mt = 0; mt < 4; mt++) af[mt] = ldfrag(&As[cur][wr * 64 + mt * 16 + l][ks + q * 8]);
#pragma unroll
      for (int nt = 0; nt < 4; nt++) {
        int row = wc * 64 + nt * 16 + l;
        bv[nt] = ldfrag((const u16*)((const char*)&Bs[cur][0][0] + row * 128 +
                                     (((ks << 1) + q * 16) ^ ((l & 7) << 4))));
      }
#pragma unroll
      for (int mt = 0; mt < 4; mt++)
#pragma unroll
        for (int nt = 0; nt < 4; nt++) acc[mt][nt] = mfma16(af[mt], bv[nt], acc[mt][nt]);
    }
    if (more) writeA(nxt);
    __syncthreads();
  }

  // epilogue: +bias, bf16 store.  D layout: row=q*4+reg, col=l.
#pragma unroll
  for (int nt = 0; nt < 4; nt++) {
    int col = n0 + wc * 64 + nt * 16 + l;
    float bvv = bias[col];
#pragma unroll
    for (int mt = 0; mt < 4; mt++)
#pragma unroll
      for (int r = 0; r < 4; r++) {
        int row = m0 + wr * 64 + mt * 16 + q * 4 + r;
        C[(size_t)row * N + col] = f2b(acc[mt][nt][r] + bvv);
      }
  }
}

// --------------------------------------------------------------------------
// Fused attention per (64-row Q tile, batch).
// LDS union: phase1 Kbuf[2][256][64] (65536B) ; phase2/3 Ps[64][264] (33792B)
//            + Kts[2][256][40] (40960B) => 74752B total.  2 blocks/CU.
// --------------------------------------------------------------------------
__global__ __launch_bounds__(256, 2) void attn_fused(
    const u16* __restrict__ Qbuf,   // [B*2048][512] bf16
    const u16* __restrict__ Kp,     // [B*256][512] bf16
    const u16* __restrict__ KpT,    // [B][512][256] bf16
    const int* __restrict__ mask,   // [B][256]
    const float* __restrict__ gamma, const float* __restrict__ beta,  // [1024] fp32
    float* __restrict__ out0,       // [B*2048][1024] fp32
    float* __restrict__ out1) {     // [B*2048][256] fp32
  __shared__ __align__(16) char smem[74752];
  u16* Ps   = (u16*)smem;            // [64][264]   (33792B) — wave-private rows
  u16* Kts0 = (u16*)(smem + 33792);  // [2][256][40] (40960B)

  int tid = threadIdx.x, wave = tid >> 6, lane = tid & 63;
  int l = lane & 15, q = lane >> 4;

  // XCD swizzle: 4 batches per XCD -> K/KpT stay in that XCD's L2.
  int chunk = gridDim.x >> 3;
  int swz = (blockIdx.x & 7) * chunk + (blockIdx.x >> 3);
  int m0 = (swz & 31) * 64, b = swz >> 5;

  const u16* Qb  = Qbuf + ((size_t)b * 2048 + m0) * 512;
  const u16* Kb  = Kp  + (size_t)b * 256 * 512;
  const u16* KTb = KpT + (size_t)b * 512 * 256;
  int sw = ((lane & 7) ^ (lane >> 3)) << 4;

  float madd[16];
#pragma unroll
  for (int nt = 0; nt < 16; nt++)
    madd[nt] = (float)(1 - mask[b * 256 + nt * 16 + l]) * -1000.0f;

  // ---- Q A-fragments: preload whole K-extent into registers (32 VGPR).
  bf16x8 af[16];
#pragma unroll
  for (int t = 0; t < 8; t++)
#pragma unroll
    for (int s = 0; s < 2; s++)
      af[t * 2 + s] = ldfrag(&Qb[(size_t)(wave * 16 + l) * 512 + t * 64 + s * 32 + q * 8]);

  auto stageK = [&](int buf, int kc) {   // 256x64 bf16 via global_load_lds
#pragma unroll
    for (int i = 0; i < 8; i++) {
      int rb = wave * 8 + i;             // 1KB chunk (8 rows) id 0..31
      int r  = rb * 8 + (lane >> 3);
      const char* src = (const char*)Kb + ((size_t)r * 512 + kc) * 2 + sw;
      gl_lds16(src, smem + buf * 32768 + rb * 1024);
    }
  };

  // ---- Phase 1: energy. Wave w owns rows w*16..w*16+15, all 256 cols.
  f32x4 accE[16];
#pragma unroll
  for (int nt = 0; nt < 16; nt++) accE[nt] = (f32x4)0.0f;

  stageK(0, 0);
  __syncthreads();
#pragma unroll
  for (int t = 0; t < 8; t++) {
    int cur = t & 1;
    if (t < 7) stageK(cur ^ 1, (t + 1) * 64);
    const char* kb = smem + cur * 32768;
    __builtin_amdgcn_s_setprio(1);
#pragma unroll
    for (int s = 0; s < 2; s++) {
      bf16x8 a = af[t * 2 + s];
#pragma unroll
      for (int nt = 0; nt < 16; nt++) {
        int row = nt * 16 + l;
        bf16x8 bv = ldfrag((const u16*)(kb + row * 128 +
                                        ((s * 64 + q * 16) ^ ((l & 7) << 4))));
        accE[nt] = mfma16(a, bv, accE[nt]);
      }
    }
    __builtin_amdgcn_s_setprio(0);
    __syncthreads();
  }

  // ---- Phase 3 staging helpers (issue-early / write-late, double-buffered)
  i32x4 kpf[4];
  auto loadKts = [&](int t) {
    int h = t >> 3, pc = (t & 7) * 32;
#pragma unroll
    for (int i = 0; i < 4; i++) {
      int r = (tid >> 2) + i * 64, c = (tid & 3) * 8;
      kpf[i] = *(const i32x4*)&KTb[(size_t)(h * 256 + r) * 256 + pc + c];
    }
  };
  auto writeKts = [&](int buf) {
#pragma unroll
    for (int i = 0; i < 4; i++) {
      int r = (tid >> 2) + i * 64, c = (tid & 3) * 8;
      *(i32x4*)&Kts0[(size_t)buf * 10240 + r * 40 + c] = kpf[i];
    }
  };
  loadKts(0);   // issue now; latency hides under softmax

  // ---- Phase 2: mask, energy out (fp32), shuffle softmax (quad rows)
  int rbase = m0 + wave * 16 + q * 4;
#pragma unroll
  for (int nt = 0; nt < 16; nt++)
#pragma unroll
    for (int r = 0; r < 4; r++) accE[nt][r] += madd[nt];

#pragma unroll
  for (int r = 0; r < 4; r++) {
    size_t rowoff = ((size_t)b * 2048 + rbase + r) * 256;
#pragma unroll
    for (int nt = 0; nt < 16; nt++) out1[rowoff + nt * 16 + l] = accE[nt][r];
  }

  float mx[4], sm[4], rs[4];
#pragma unroll
  for (int r = 0; r < 4; r++) mx[r] = -1e30f;
#pragma unroll
  for (int nt = 0; nt < 16; nt++)
#pragma unroll
    for (int r = 0; r < 4; r++) mx[r] = fmaxf(mx[r], accE[nt][r]);
#pragma unroll
  for (int off = 1; off < 16; off <<= 1)
#pragma unroll
    for (int r = 0; r < 4; r++) mx[r] = fmaxf(mx[r], __shfl_xor(mx[r], off));
#pragma unroll
  for (int r = 0; r < 4; r++) sm[r] = 0.0f;
#pragma unroll
  for (int nt = 0; nt < 16; nt++)
#pragma unroll
    for (int r = 0; r < 4; r++) {
      float p = __expf(accE[nt][r] - mx[r]);
      accE[nt][r] = p;
      sm[r] += p;
    }
#pragma unroll
  for (int off = 1; off < 16; off <<= 1)
#pragma unroll
    for (int r = 0; r < 4; r++) sm[r] += __shfl_xor(sm[r], off);
#pragma unroll
  for (int r = 0; r < 4; r++) rs[r] = 1.0f / sm[r];

  // Ps rows are wave-private; Kbuf reads all ended at the phase-1 barrier.
#pragma unroll
  for (int r = 0; r < 4; r++)
#pragma unroll
    for (int nt = 0; nt < 16; nt++)
      Ps[(wave * 16 + q * 4 + r) * 264 + nt * 16 + l] = f2b(accE[nt][r] * rs[r]);

  writeKts(0);
  __syncthreads();

  // ---- Phase 3: O = P @ Kp via KpT.  1 barrier/step, dbuf Kts.
  f32x4 accO[32];
#pragma unroll
  for (int g = 0; g < 32; g++) accO[g] = (f32x4)0.0f;
#pragma unroll
  for (int t = 0; t < 16; t++) {
    int cur = t & 1, h = t >> 3, pc = (t & 7) * 32;
    if (t < 15) loadKts(t + 1);
    bf16x8 ps = ldfrag(&Ps[(wave * 16 + l) * 264 + pc + q * 8]);
    __builtin_amdgcn_s_setprio(1);
#pragma unroll
    for (int nt = 0; nt < 16; nt++) {
      bf16x8 bv = ldfrag(&Kts0[(size_t)cur * 10240 + (nt * 16 + l) * 40 + q * 8]);
      accO[h * 16 + nt] = mfma16(ps, bv, accO[h * 16 + nt]);
    }
    __builtin_amdgcn_s_setprio(0);
    if (t < 15) writeKts(cur ^ 1);
    __syncthreads();
  }

  // ---- Phase 4: LayerNorm over concat(O[512], Q[512]) per row.
  float s1[4], s2[4];
#pragma unroll
  for (int r = 0; r < 4; r++) { s1[r] = 0.0f; s2[r] = 0.0f; }
#pragma unroll
  for (int g = 0; g < 32; g++)
#pragma unroll
    for (int r = 0; r < 4; r++) { float v = accO[g][r]; s1[r] += v; s2[r] += v * v; }
#pragma unroll
  for (int r = 0; r < 4; r++) {
    const u16* qr = Qb + (size_t)(wave * 16 + q * 4 + r) * 512;
#pragma unroll
    for (int p = 0; p < 4; p++) {
      bf16x8 qv = ldfrag(&qr[p * 128 + l * 8]);
#pragma unroll
      for (int j = 0; j < 8; j++) { float v = (float)qv[j]; s1[r] += v; s2[r] += v * v; }
    }
  }
#pragma unroll
  for (int off = 1; off < 16; off <<= 1)
#pragma unroll
    for (int r = 0; r < 4; r++) {
      s1[r] += __shfl_xor(s1[r], off);
      s2[r] += __shfl_xor(s2[r], off);
    }
#pragma unroll
  for (int r = 0; r < 4; r++) {
    float mean = s1[r] * (1.0f / 1024.0f);
    float var  = s2[r] * (1.0f / 1024.0f) - mean * mean;
    float rstd = rsqrtf(var + 1e-5f);
    size_t rowbase = ((size_t)b * 2048 + rbase + r) * 1024;
#pragma unroll
    for (int g = 0; g < 32; g++) {
      int col = g * 16 + l;
      out0[rowbase + col] = (accO[g][r] - mean) * rstd * gamma[col] + beta[col];
    }
    const u16* qr = Qb + (size_t)(wave * 16 + q * 4 + r) * 512;
#pragma unroll
    for (int p = 0; p < 4; p++) {
      bf16x8 qv = ldfrag(&qr[p * 128 + l * 8]);
      float ov[8];
#pragma unroll
      for (int j = 0; j < 8; j++) {
        int col = 512 + p * 128 + l * 8 + j;
        ov[j] = ((float)qv[j] - mean) * rstd * gamma[col] + beta[col];
      }
      *(f32x4*)&out0[rowbase + 512 + p * 128 + l * 8] = *(f32x4*)&ov[0];
      *(f32x4*)&out0[rowbase + 516 + p * 128 + l * 8] = *(f32x4*)&ov[4];
    }
  }
}

// --------------------------------------------------------------------------
extern "C" void kernel_launch(void* const* d_in, const int* in_sizes, int n_in,
                              void* d_out, int out_size, void* d_ws, size_t ws_size,
                              hipStream_t stream) {
  (void)in_sizes; (void)n_in; (void)out_size; (void)ws_size;
  const float* frame = (const float*)d_in[0];   // [32][2048][768] fp32
  const float* phn   = (const float*)d_in[1];   // [32][256][512]  fp32
  const int*   msk   = (const int*)d_in[2];     // [32][256] int32
  const float* Wq    = (const float*)d_in[3];   // [768][512] fp32
  const float* bq    = (const float*)d_in[4];   // [512]
  const float* Wk    = (const float*)d_in[5];   // [512][512]
  const float* bk    = (const float*)d_in[6];   // [512]
  const float* gamma = (const float*)d_in[7];   // [1024]
  const float* beta  = (const float*)d_in[8];   // [1024]

  u16* ws   = (u16*)d_ws;
  u16* WqT  = ws;              // [512][768] bf16      393216 elems
  u16* WkT  = ws + 393216;     // [512][512]           262144
  u16* Qbuf = ws + 655360;     // [65536][512]         33554432
  u16* Kp   = ws + 34209792;   // [8192][512]          4194304
  u16* KpT  = ws + 38404096;   // [32][512][256]       4194304  (end: 85.2 MB)

  float* out0 = (float*)d_out;                      // [32*2048][1024] fp32
  float* out1 = out0 + (size_t)32 * 2048 * 1024;    // [32*2048][256]  fp32

  transpose_f32_bf16<<<dim3(16, 24, 1), dim3(32, 8, 1), 0, stream>>>(Wq, WqT, 768, 512);
  transpose_f32_bf16<<<dim3(16, 16, 1), dim3(32, 8, 1), 0, stream>>>(Wk, WkT, 512, 512);
  gemm_bias_bt<<<dim3(2048, 1, 1), dim3(256, 1, 1), 0, stream>>>(frame, WqT, bq, Qbuf, 65536, 512, 768);
  gemm_bias_bt<<<dim3(256, 1, 1), dim3(256, 1, 1), 0, stream>>>(phn, WkT, bk, Kp, 8192, 512, 512);
  transpose_bf16<<<dim3(16, 8, 32), dim3(32, 8, 1), 0, stream>>>(Kp, KpT, 256, 512, 131072, 131072);
  attn_fused<<<dim3(1024, 1, 1), dim3(256, 1, 1), 0, stream>>>(Qbuf, Kp, KpT, msk, gamma, beta, out0, out1);
}